// Round 4
// baseline (32117.731 us; speedup 1.0000x reference)
//
#include <hip/hip_runtime.h>
#include <math.h>

#define BDIM 1024
#define DDIM 512
#define VDIM 128
#define TDIM 201
#define FD   2048            // 4*D
#define LN_EPS 1e-5f
#define LOSCALE 4096.0f
#define INV_LOSCALE (1.0f/4096.0f)
#define NBLK 512             // persistent grid: 2 blocks/CU, all co-resident

// ws layout in floats (total 5,308,416 floats = 20.25 MiB)
#define OFF_C   0            // B*D      c state
#define OFF_CTX 524288       // B*D      context (constant across steps)
#define OFF_E   1048576      // V*FD     E = embed @ W_ih^T + b_ih + b_hh
#define OFF_CP  1310720      // B*V      ctx @ proj^T
#define OFF_LC  1441792      // B*V      current logits (for argmax)
#define OFF_G   1572864      // B*FD     raw gates (before E add)
#define OFF_AHI 3670016      // 64*16*64*8 f16 = 262144 floats: A hi frags
#define OFF_ALO 3932160      // A lo frags (scaled by 4096)
#define OFF_BHI 4194304      // 136*16*64*8 f16 = 557056 floats: B hi frags
#define OFF_BLO 4751360      // B lo frags (scaled by 4096)

typedef _Float16 v8hf __attribute__((ext_vector_type(8)));
typedef float    v4f  __attribute__((ext_vector_type(4)));

// Barrier state lives in a device global (ws is re-poisoned every launch;
// k_init re-zeroes this every call, so every call does identical work).
__device__ unsigned g_bar[2];      // [0] = arrival counter, [1] = generation

// Fragment-major layouts (16x16x32 f16 MFMA):
//   A: lane l holds A[m = mt*16 + (l&15)][k = kt*32 + (l>>4)*8 + j]
//      frag[((mt*16 + kt)*64 + l)*8 + j]      (B identical with n for m)
//   C/D: col = lane&15, row = (lane>>4)*4 + reg   (m89/m91 verified)
//
// Precision: x = hi + lo/4096, |err| <= 2^-24|x|.
// acc1 += hi*hi ; acc2 += hi*lo + lo*hi ; result = acc1 + acc2/4096.
// x4096 keeps lo in f16 normal range (subnormal flush hazard on MFMA).

__device__ __forceinline__ void split_write(float x, _Float16* hiArr, _Float16* loArr,
                                            int row, int k)
{
    _Float16 hi = (_Float16)x;
    _Float16 lo = (_Float16)((x - (float)hi) * LOSCALE);
    int lane = (row & 15) | (((k >> 3) & 3) << 4);
    size_t idx = ((size_t)((row >> 4) * 16 + (k >> 5)) * 64 + lane) * 8 + (k & 7);
    hiArr[idx] = hi;
    loArr[idx] = lo;
}

// ---------------------------------------------------------------------------
// Grid barrier for the persistent kernel. Arrival fetch_add(ACQ_REL, agent)
// emits the L2 writeback that publishes this block's ordinary stores to the
// coherent point (per-XCD L2s are NOT cross-coherent); the final acquire
// fence invalidates stale L1/L2 lines before the next phase reads.
// ---------------------------------------------------------------------------
__device__ __forceinline__ void grid_barrier()
{
    __syncthreads();
    if (threadIdx.x == 0) {
        unsigned g = __hip_atomic_load(&g_bar[1], __ATOMIC_RELAXED,
                                       __HIP_MEMORY_SCOPE_AGENT);
        unsigned a = __hip_atomic_fetch_add(&g_bar[0], 1u, __ATOMIC_ACQ_REL,
                                            __HIP_MEMORY_SCOPE_AGENT);
        if (a == NBLK - 1u) {
            __hip_atomic_store(&g_bar[0], 0u, __ATOMIC_RELAXED,
                               __HIP_MEMORY_SCOPE_AGENT);
            __hip_atomic_fetch_add(&g_bar[1], 1u, __ATOMIC_RELEASE,
                                   __HIP_MEMORY_SCOPE_AGENT);
        } else {
            while (__hip_atomic_load(&g_bar[1], __ATOMIC_RELAXED,
                                     __HIP_MEMORY_SCOPE_AGENT) == g) {
                __builtin_amdgcn_s_sleep(1);
            }
        }
        __builtin_amdgcn_fence(__ATOMIC_ACQUIRE, "agent");
    }
    __syncthreads();
}

// ---------------------------------------------------------------------------
// init: LayerNorm(pooled) -> h0 ; c0 = 0 ; softmax(fm@wf) -> context ;
// A-fragments of (h0 + ctx); block 0 zeroes the barrier state.
// Softmax shift-invariance kills the h@wh + attn_b term -> ctx constant.
// ---------------------------------------------------------------------------
__global__ void k_init(const float* __restrict__ fm, const float* __restrict__ pooled,
                       const float* __restrict__ gamma, const float* __restrict__ beta,
                       const float* __restrict__ attn_w, float* __restrict__ ws)
{
    int b = blockIdx.x;
    int t = threadIdx.x;                 // 256 threads
    if (b == 0 && t < 2) g_bar[t] = 0u;

    __shared__ float red[256];
    __shared__ float s_sc[49];
    __shared__ float s_aw[49];
    __shared__ float s_ctx[DDIM];

    const float* prow = pooled + (size_t)b * DDIM;
    float x0 = prow[t], x1 = prow[t + 256];
    red[t] = x0 + x1;
    __syncthreads();
    for (int s = 128; s > 0; s >>= 1) { if (t < s) red[t] += red[t + s]; __syncthreads(); }
    float mu = red[0] * (1.0f / DDIM);
    __syncthreads();
    float d0 = x0 - mu, d1 = x1 - mu;
    red[t] = d0 * d0 + d1 * d1;
    __syncthreads();
    for (int s = 128; s > 0; s >>= 1) { if (t < s) red[t] += red[t + s]; __syncthreads(); }
    float rstd = rsqrtf(red[0] * (1.0f / DDIM) + LN_EPS);

    float h0 = d0 * rstd * gamma[t]       + beta[t];
    float h1 = d1 * rstd * gamma[t + 256] + beta[t + 256];

    float* c = ws + OFF_C + (size_t)b * DDIM;
    c[t] = 0.0f;
    c[t + 256] = 0.0f;

    if (t < 49) {                        // scores[k] = sum_d fm[b,d,k] * wf[d]
        const float* base = fm + (size_t)b * DDIM * 49 + t;
        float acc = 0.0f;
        for (int d = 0; d < DDIM; ++d) acc += base[(size_t)d * 49] * attn_w[d];
        s_sc[t] = acc;
    }
    __syncthreads();
    if (t == 0) {
        float mx = s_sc[0];
        for (int k = 1; k < 49; ++k) mx = fmaxf(mx, s_sc[k]);
        float sum = 0.0f;
        for (int k = 0; k < 49; ++k) { float e = expf(s_sc[k] - mx); s_aw[k] = e; sum += e; }
        float inv = 1.0f / sum;
        for (int k = 0; k < 49; ++k) s_aw[k] *= inv;
    }
    __syncthreads();

    float* ctx = ws + OFF_CTX + (size_t)b * DDIM;
    for (int d = t; d < DDIM; d += 256) {
        const float* base = fm + ((size_t)b * DDIM + d) * 49;
        float acc = 0.0f;
        for (int k = 0; k < 49; ++k) acc += s_aw[k] * base[k];
        ctx[d] = acc;
        s_ctx[d] = acc;
    }
    __syncthreads();

    _Float16* Ahi = (_Float16*)(ws + OFF_AHI);
    _Float16* Alo = (_Float16*)(ws + OFF_ALO);
    split_write(h0 + s_ctx[t],       Ahi, Alo, b, t);
    split_write(h1 + s_ctx[t + 256], Ahi, Alo, b, t + 256);
}

// ---------------------------------------------------------------------------
// E[v, n] = sum_d embed[v,d] * W_ih[n,d] + b_ih[n] + b_hh[n]   (128 x 2048)
// ---------------------------------------------------------------------------
__global__ void k_E(const float* __restrict__ embed, const float* __restrict__ W_ih,
                    const float* __restrict__ b_ih, const float* __restrict__ b_hh,
                    float* __restrict__ ws)
{
    int n = blockIdx.x;
    int t = threadIdx.x;                 // 256 threads
    __shared__ float wrow[DDIM];
    wrow[t]       = W_ih[(size_t)n * DDIM + t];
    wrow[t + 256] = W_ih[(size_t)n * DDIM + t + 256];
    __syncthreads();
    if (t < VDIM) {
        const float* er = embed + (size_t)t * DDIM;
        float acc = 0.0f;
        for (int d = 0; d < DDIM; ++d) acc += er[d] * wrow[d];
        ws[OFF_E + (size_t)t * FD + n] = acc + b_ih[n] + b_hh[n];
    }
}

// ---------------------------------------------------------------------------
// ctxproj[b, v] = sum_d ctx[b,d] * proj_w[v,d]
// ---------------------------------------------------------------------------
__global__ void k_cp(const float* __restrict__ proj_w, float* __restrict__ ws)
{
    int b = blockIdx.x;
    int t = threadIdx.x;                 // 128 threads, one per v
    __shared__ float crow[DDIM];
    const float* ctx = ws + OFF_CTX + (size_t)b * DDIM;
    for (int d = t; d < DDIM; d += 128) crow[d] = ctx[d];
    __syncthreads();
    const float* pr = proj_w + (size_t)t * DDIM;
    float acc = 0.0f;
    for (int d = 0; d < DDIM; ++d) acc += crow[d] * pr[d];
    ws[OFF_CP + (size_t)b * VDIM + t] = acc;
}

// ---------------------------------------------------------------------------
// One-time: [W_hh | proj_w] (2176 x 512) -> fragment-major f16 hi/lo
// ---------------------------------------------------------------------------
__global__ void k_bsetup(const float* __restrict__ W_hh, const float* __restrict__ proj_w,
                         float* __restrict__ ws)
{
    int n = blockIdx.x;                  // 0..2175
    int t = threadIdx.x;                 // 256
    const float* src = (n < FD) ? (W_hh + (size_t)n * DDIM)
                                : (proj_w + (size_t)(n - FD) * DDIM);
    _Float16* Bhi = (_Float16*)(ws + OFF_BHI);
    _Float16* Blo = (_Float16*)(ws + OFF_BLO);
    for (int k = t; k < DDIM; k += 256)
        split_write(src[k], Bhi, Blo, n, k);
}

// ---------------------------------------------------------------------------
// One GEMM job: 64-row x 64-col tile of C = (h+ctx) @ [W_hh^T | proj_w^T].
// Wave w of the block handles rows [mt*16, mt*16+16), mt = rt*4+w.
// ct < 32 -> gates columns ; ct >= 32 -> logits columns (tout = tau-1).
// ---------------------------------------------------------------------------
__device__ __forceinline__ void gemm_job(int rt, int ct, int w, int lane,
                                         const float* __restrict__ proj_b,
                                         float* __restrict__ ws,
                                         float* __restrict__ out, int tau)
{
    int mt  = rt * 4 + w;
    int ntb = ct * 4;

    const v8hf* Ah = (const v8hf*)(ws + OFF_AHI);
    const v8hf* Al = (const v8hf*)(ws + OFF_ALO);
    const v8hf* Bh = (const v8hf*)(ws + OFF_BHI);
    const v8hf* Bl = (const v8hf*)(ws + OFF_BLO);

    v4f acc1[4], acc2[4];
#pragma unroll
    for (int nt = 0; nt < 4; ++nt) {
        acc1[nt] = (v4f){0.f, 0.f, 0.f, 0.f};
        acc2[nt] = (v4f){0.f, 0.f, 0.f, 0.f};
    }

    int aBase = mt * 16;
    v8hf ah = Ah[(aBase + 0) * 64 + lane];
    v8hf al = Al[(aBase + 0) * 64 + lane];
    v8hf bh[4], bl[4];
#pragma unroll
    for (int nt = 0; nt < 4; ++nt) {
        bh[nt] = Bh[((ntb + nt) * 16 + 0) * 64 + lane];
        bl[nt] = Bl[((ntb + nt) * 16 + 0) * 64 + lane];
    }

#pragma unroll
    for (int kt = 0; kt < 16; ++kt) {
        v8hf nah, nal, nbh[4], nbl[4];
        if (kt < 15) {
            int k1 = kt + 1;
            nah = Ah[(aBase + k1) * 64 + lane];
            nal = Al[(aBase + k1) * 64 + lane];
#pragma unroll
            for (int nt = 0; nt < 4; ++nt) {
                nbh[nt] = Bh[((ntb + nt) * 16 + k1) * 64 + lane];
                nbl[nt] = Bl[((ntb + nt) * 16 + k1) * 64 + lane];
            }
        }
#pragma unroll
        for (int nt = 0; nt < 4; ++nt) {
            acc1[nt] = __builtin_amdgcn_mfma_f32_16x16x32_f16(ah, bh[nt], acc1[nt], 0, 0, 0);
            acc2[nt] = __builtin_amdgcn_mfma_f32_16x16x32_f16(ah, bl[nt], acc2[nt], 0, 0, 0);
            acc2[nt] = __builtin_amdgcn_mfma_f32_16x16x32_f16(al, bh[nt], acc2[nt], 0, 0, 0);
        }
        if (kt < 15) {
            ah = nah; al = nal;
#pragma unroll
            for (int nt = 0; nt < 4; ++nt) { bh[nt] = nbh[nt]; bl[nt] = nbl[nt]; }
        }
    }

    int nloc = lane & 15;
    int mrow = mt * 16 + (lane >> 4) * 4;
    if (ntb < 128) {                     // gates tiles
        float* g = ws + OFF_G;
#pragma unroll
        for (int nt = 0; nt < 4; ++nt) {
            int n = (ntb + nt) * 16 + nloc;
#pragma unroll
            for (int r = 0; r < 4; ++r)
                g[(size_t)(mrow + r) * FD + n] = acc1[nt][r] + acc2[nt][r] * INV_LOSCALE;
        }
    } else {                             // logits tiles
        int tout = tau - 1;
#pragma unroll
        for (int nt = 0; nt < 4; ++nt) {
            int v = (ntb + nt) * 16 + nloc - FD;
#pragma unroll
            for (int r = 0; r < 4; ++r) {
                int b = mrow + r;
                float val = acc1[nt][r] + acc2[nt][r] * INV_LOSCALE;
                float lg = val - ws[OFF_CP + (size_t)b * VDIM + v] + proj_b[v];
                if (tout >= 0) {
                    out[((size_t)b * VDIM + v) * TDIM + tout] = lg;
                    ws[OFF_LC + (size_t)b * VDIM + v] = lg;
                }
            }
        }
    }
}

// ---------------------------------------------------------------------------
// Persistent kernel: all 202 ticks. Per tick:
//   phase G: grid-stride over 544 GEMM jobs (16 rt x 34 ct)   | barrier
//   phase P: 2 rows/block: argmax -> E-gather -> LSTM -> A-frags | barrier
// tau==0: no logits jobs (no logits yet); tau==201: logits jobs only.
// Every block executes the same barrier sequence -> no deadlock path.
// ---------------------------------------------------------------------------
__global__ __launch_bounds__(256, 2) void k_persist(
        const float* __restrict__ proj_b, const int* __restrict__ sos_p,
        float* __restrict__ ws, float* __restrict__ out)
{
    int blk = blockIdx.x;
    int tid = threadIdx.x;
    int w = tid >> 6, lane = tid & 63;
    int sos = sos_p[0];

    __shared__ float s_v[2][VDIM];
    __shared__ int   s_id[2];

    for (int tau = 0; tau <= 201; ++tau) {
        // ---------------- phase G ----------------
        for (int j = blk; j < 544; j += NBLK) {
            int rt = j & 15, ct = j >> 4;
            bool isLogit = (ct >= 32);
            if (tau == 0 && isLogit) continue;
            if (tau == 201 && !isLogit) continue;
            gemm_job(rt, ct, w, lane, proj_b, ws, out, tau);
        }
        grid_barrier();

        // ---------------- phase P ----------------
        if (tau < 201) {
            int half = tid >> 7;         // 0 or 1
            int ht = tid & 127;
            int row = blk * 2 + half;

            if (tau > 0) s_v[half][ht] = ws[OFF_LC + (size_t)row * VDIM + ht];
            __syncthreads();
            if (ht == 0) {
                if (tau > 0) {
                    float best = s_v[half][0];
                    int bi = 0;
                    for (int v = 1; v < VDIM; ++v)
                        if (s_v[half][v] > best) { best = s_v[half][v]; bi = v; }
                    s_id[half] = bi;
                } else {
                    s_id[half] = sos;
                }
            }
            __syncthreads();
            int id = s_id[half];

            const float* g   = ws + OFF_G   + (size_t)row * FD;
            const float* E   = ws + OFF_E   + (size_t)id * FD;
            const float* ctx = ws + OFF_CTX + (size_t)row * DDIM;
            float* c = ws + OFF_C + (size_t)row * DDIM;
            _Float16* Ahi = (_Float16*)(ws + OFF_AHI);
            _Float16* Alo = (_Float16*)(ws + OFF_ALO);

            for (int d = ht; d < DDIM; d += 128) {
                float gi = g[d]            + E[d];
                float gf = g[d + DDIM]     + E[d + DDIM];
                float gg = g[d + 2 * DDIM] + E[d + 2 * DDIM];
                float go = g[d + 3 * DDIM] + E[d + 3 * DDIM];
                float cv = c[d];
                float si = 1.0f / (1.0f + expf(-gi));
                float sf = 1.0f / (1.0f + expf(-gf));
                float so = 1.0f / (1.0f + expf(-go));
                float cn = sf * cv + si * tanhf(gg);
                c[d] = cn;
                float hn = so * tanhf(cn);
                split_write(hn + ctx[d], Ahi, Alo, row, d);
            }
            grid_barrier();
        }
    }
}

extern "C" void kernel_launch(void* const* d_in, const int* in_sizes, int n_in,
                              void* d_out, int out_size, void* d_ws, size_t ws_size,
                              hipStream_t stream)
{
    const float* fm     = (const float*)d_in[0];
    const float* pooled = (const float*)d_in[1];
    const float* gamma  = (const float*)d_in[2];
    const float* beta   = (const float*)d_in[3];
    const float* W_ih   = (const float*)d_in[4];
    const float* W_hh   = (const float*)d_in[5];
    const float* b_ih   = (const float*)d_in[6];
    const float* b_hh   = (const float*)d_in[7];
    const float* embed  = (const float*)d_in[8];
    const float* attn_w = (const float*)d_in[9];
    // d_in[10] = attn_b : provably unused (softmax shift invariance)
    const float* proj_w = (const float*)d_in[11];
    const float* proj_b = (const float*)d_in[12];
    const int*   sos_p  = (const int*)d_in[13];

    float* ws  = (float*)d_ws;
    float* out = (float*)d_out;

    k_init<<<BDIM, 256, 0, stream>>>(fm, pooled, gamma, beta, attn_w, ws);
    k_E<<<FD, 256, 0, stream>>>(embed, W_ih, b_ih, b_hh, ws);
    k_cp<<<BDIM, 128, 0, stream>>>(proj_w, ws);
    k_bsetup<<<FD + VDIM, 256, 0, stream>>>(W_hh, proj_w, ws);

    k_persist<<<NBLK, 256, 0, stream>>>(proj_b, sos_p, ws, out);
}

// Round 5
// 29799.655 us; speedup vs baseline: 1.0778x; 1.0778x over previous
//
#include <hip/hip_runtime.h>
#include <math.h>

#define BDIM 1024
#define DDIM 512
#define VDIM 128
#define TDIM 201
#define FD   2048            // 4*D
#define LN_EPS 1e-5f
#define LOSCALE 4096.0f
#define INV_LOSCALE (1.0f/4096.0f)

// ws layout in floats (total 5,308,416 floats = 20.25 MiB)
#define OFF_C   0            // B*D      c state
#define OFF_CTX 524288       // B*D      context (constant across steps)
#define OFF_E   1048576      // V*FD     E = embed @ W_ih^T + b_ih + b_hh
#define OFF_CP  1310720      // B*V      ctx @ proj^T
#define OFF_LC  1441792      // B*V      current logits (write-through region)
#define OFF_G   1572864      // B*FD     raw gates (write-through region)
#define OFF_AHI 3670016      // 64*16*64*8 f16: A hi frags
#define OFF_ALO 3932160      // A lo frags (scaled by 4096)
#define OFF_BHI 4194304      // 136*16*64*8 f16: B hi frags
#define OFF_BLO 4751360      // B lo frags (scaled by 4096)

typedef _Float16 v8hf __attribute__((ext_vector_type(8)));
typedef float    v4f  __attribute__((ext_vector_type(4)));

// Per-(tick,rt) arrival counters. Device global (ws is 0xAA-poisoned each
// call); k_zero re-zeroes every call -> identical work per call.
__device__ unsigned g_cnt[201 * 16];

// Write-through (agent-scope relaxed atomic) accessors: stores go past the
// per-XCD L2 to the coherent point; loads bypass stale L1/L2. The gates/LC
// buffers are ONLY ever touched through these within a kernel, so no line
// of them is ever dirty/stale in any cache -> no wbl2/buffer_inv needed
// (the round-4 lesson: those cache ops at grid-barrier scale cost 150 us/tick).
__device__ __forceinline__ void st_wt(float* p, float v) {
    __hip_atomic_store(p, v, __ATOMIC_RELAXED, __HIP_MEMORY_SCOPE_AGENT);
}
__device__ __forceinline__ float ld_wt(const float* p) {
    return __hip_atomic_load(p, __ATOMIC_RELAXED, __HIP_MEMORY_SCOPE_AGENT);
}

// Fragment-major layouts (16x16x32 f16 MFMA):
//   A: lane l holds A[m = mt*16 + (l&15)][k = kt*32 + (l>>4)*8 + j]
//      frag[((mt*16 + kt)*64 + l)*8 + j]      (B identical with n for m)
//   C/D: col = lane&15, row = (lane>>4)*4 + reg   (m89/m91 verified)
// Precision: x = hi + lo/4096, |err| <= 2^-24|x|;
// acc1 += hi*hi ; acc2 += hi*lo + lo*hi ; result = acc1 + acc2/4096.

__device__ __forceinline__ void split_write(float x, _Float16* hiArr, _Float16* loArr,
                                            int row, int k)
{
    _Float16 hi = (_Float16)x;
    _Float16 lo = (_Float16)((x - (float)hi) * LOSCALE);
    int lane = (row & 15) | (((k >> 3) & 3) << 4);
    size_t idx = ((size_t)((row >> 4) * 16 + (k >> 5)) * 64 + lane) * 8 + (k & 7);
    hiArr[idx] = hi;
    loArr[idx] = lo;
}

// ---------------------------------------------------------------------------
// init: LayerNorm(pooled) -> h0 ; c0 = 0 ; softmax(fm@wf) -> context ;
// A-fragments of (h0 + ctx). Softmax shift-invariance kills h@wh + attn_b.
// ---------------------------------------------------------------------------
__global__ void k_init(const float* __restrict__ fm, const float* __restrict__ pooled,
                       const float* __restrict__ gamma, const float* __restrict__ beta,
                       const float* __restrict__ attn_w, float* __restrict__ ws)
{
    int b = blockIdx.x;
    int t = threadIdx.x;                 // 256 threads
    __shared__ float red[256];
    __shared__ float s_sc[49];
    __shared__ float s_aw[49];
    __shared__ float s_ctx[DDIM];

    const float* prow = pooled + (size_t)b * DDIM;
    float x0 = prow[t], x1 = prow[t + 256];
    red[t] = x0 + x1;
    __syncthreads();
    for (int s = 128; s > 0; s >>= 1) { if (t < s) red[t] += red[t + s]; __syncthreads(); }
    float mu = red[0] * (1.0f / DDIM);
    __syncthreads();
    float d0 = x0 - mu, d1 = x1 - mu;
    red[t] = d0 * d0 + d1 * d1;
    __syncthreads();
    for (int s = 128; s > 0; s >>= 1) { if (t < s) red[t] += red[t + s]; __syncthreads(); }
    float rstd = rsqrtf(red[0] * (1.0f / DDIM) + LN_EPS);

    float h0 = d0 * rstd * gamma[t]       + beta[t];
    float h1 = d1 * rstd * gamma[t + 256] + beta[t + 256];

    float* c = ws + OFF_C + (size_t)b * DDIM;
    c[t] = 0.0f;
    c[t + 256] = 0.0f;

    if (t < 49) {                        // scores[k] = sum_d fm[b,d,k] * wf[d]
        const float* base = fm + (size_t)b * DDIM * 49 + t;
        float acc = 0.0f;
        for (int d = 0; d < DDIM; ++d) acc += base[(size_t)d * 49] * attn_w[d];
        s_sc[t] = acc;
    }
    __syncthreads();
    if (t == 0) {
        float mx = s_sc[0];
        for (int k = 1; k < 49; ++k) mx = fmaxf(mx, s_sc[k]);
        float sum = 0.0f;
        for (int k = 0; k < 49; ++k) { float e = expf(s_sc[k] - mx); s_aw[k] = e; sum += e; }
        float inv = 1.0f / sum;
        for (int k = 0; k < 49; ++k) s_aw[k] *= inv;
    }
    __syncthreads();

    float* ctx = ws + OFF_CTX + (size_t)b * DDIM;
    for (int d = t; d < DDIM; d += 256) {
        const float* base = fm + ((size_t)b * DDIM + d) * 49;
        float acc = 0.0f;
        for (int k = 0; k < 49; ++k) acc += s_aw[k] * base[k];
        ctx[d] = acc;
        s_ctx[d] = acc;
    }
    __syncthreads();

    _Float16* Ahi = (_Float16*)(ws + OFF_AHI);
    _Float16* Alo = (_Float16*)(ws + OFF_ALO);
    split_write(h0 + s_ctx[t],       Ahi, Alo, b, t);
    split_write(h1 + s_ctx[t + 256], Ahi, Alo, b, t + 256);
}

// ---------------------------------------------------------------------------
// E[v, n] = sum_d embed[v,d] * W_ih[n,d] + b_ih[n] + b_hh[n]   (128 x 2048)
// ---------------------------------------------------------------------------
__global__ void k_E(const float* __restrict__ embed, const float* __restrict__ W_ih,
                    const float* __restrict__ b_ih, const float* __restrict__ b_hh,
                    float* __restrict__ ws)
{
    int n = blockIdx.x;
    int t = threadIdx.x;                 // 256 threads
    __shared__ float wrow[DDIM];
    wrow[t]       = W_ih[(size_t)n * DDIM + t];
    wrow[t + 256] = W_ih[(size_t)n * DDIM + t + 256];
    __syncthreads();
    if (t < VDIM) {
        const float* er = embed + (size_t)t * DDIM;
        float acc = 0.0f;
        for (int d = 0; d < DDIM; ++d) acc += er[d] * wrow[d];
        ws[OFF_E + (size_t)t * FD + n] = acc + b_ih[n] + b_hh[n];
    }
}

// ---------------------------------------------------------------------------
// ctxproj[b, v] = sum_d ctx[b,d] * proj_w[v,d]
// ---------------------------------------------------------------------------
__global__ void k_cp(const float* __restrict__ proj_w, float* __restrict__ ws)
{
    int b = blockIdx.x;
    int t = threadIdx.x;                 // 128 threads, one per v
    __shared__ float crow[DDIM];
    const float* ctx = ws + OFF_CTX + (size_t)b * DDIM;
    for (int d = t; d < DDIM; d += 128) crow[d] = ctx[d];
    __syncthreads();
    const float* pr = proj_w + (size_t)t * DDIM;
    float acc = 0.0f;
    for (int d = 0; d < DDIM; ++d) acc += crow[d] * pr[d];
    ws[OFF_CP + (size_t)b * VDIM + t] = acc;
}

// ---------------------------------------------------------------------------
// One-time: [W_hh | proj_w] (2176 x 512) -> fragment-major f16 hi/lo
// ---------------------------------------------------------------------------
__global__ void k_bsetup(const float* __restrict__ W_hh, const float* __restrict__ proj_w,
                         float* __restrict__ ws)
{
    int n = blockIdx.x;                  // 0..2175
    int t = threadIdx.x;                 // 256
    const float* src = (n < FD) ? (W_hh + (size_t)n * DDIM)
                                : (proj_w + (size_t)(n - FD) * DDIM);
    _Float16* Bhi = (_Float16*)(ws + OFF_BHI);
    _Float16* Blo = (_Float16*)(ws + OFF_BLO);
    for (int k = t; k < DDIM; k += 256)
        split_write(src[k], Bhi, Blo, n, k);
}

// ---------------------------------------------------------------------------
// Zero the arrival counters (every call; device globals persist).
// ---------------------------------------------------------------------------
__global__ void k_zero()
{
    int i = blockIdx.x * 256 + threadIdx.x;
    if (i < 201 * 16) g_cnt[i] = 0u;
}

// ---------------------------------------------------------------------------
// One GEMM job: 64-row x 64-col tile of C = (h+ctx) @ [W_hh^T | proj_w^T].
// Wave w handles rows [mt*16, mt*16+16), mt = rt*4+w.
// Gates / LC written WRITE-THROUGH (read by the P phase in this kernel,
// possibly on another XCD); out written ordinarily (host reads after kernel).
// ---------------------------------------------------------------------------
__device__ __forceinline__ void gemm_job(int rt, int ct, int w, int lane,
                                         const float* __restrict__ proj_b,
                                         float* __restrict__ ws,
                                         float* __restrict__ out, int tau)
{
    int mt  = rt * 4 + w;
    int ntb = ct * 4;

    const v8hf* Ah = (const v8hf*)(ws + OFF_AHI);
    const v8hf* Al = (const v8hf*)(ws + OFF_ALO);
    const v8hf* Bh = (const v8hf*)(ws + OFF_BHI);
    const v8hf* Bl = (const v8hf*)(ws + OFF_BLO);

    v4f acc1[4], acc2[4];
#pragma unroll
    for (int nt = 0; nt < 4; ++nt) {
        acc1[nt] = (v4f){0.f, 0.f, 0.f, 0.f};
        acc2[nt] = (v4f){0.f, 0.f, 0.f, 0.f};
    }

    int aBase = mt * 16;
    v8hf ah = Ah[(aBase + 0) * 64 + lane];
    v8hf al = Al[(aBase + 0) * 64 + lane];
    v8hf bh[4], bl[4];
#pragma unroll
    for (int nt = 0; nt < 4; ++nt) {
        bh[nt] = Bh[((ntb + nt) * 16 + 0) * 64 + lane];
        bl[nt] = Bl[((ntb + nt) * 16 + 0) * 64 + lane];
    }

#pragma unroll
    for (int kt = 0; kt < 16; ++kt) {
        v8hf nah, nal, nbh[4], nbl[4];
        if (kt < 15) {
            int k1 = kt + 1;
            nah = Ah[(aBase + k1) * 64 + lane];
            nal = Al[(aBase + k1) * 64 + lane];
#pragma unroll
            for (int nt = 0; nt < 4; ++nt) {
                nbh[nt] = Bh[((ntb + nt) * 16 + k1) * 64 + lane];
                nbl[nt] = Bl[((ntb + nt) * 16 + k1) * 64 + lane];
            }
        }
#pragma unroll
        for (int nt = 0; nt < 4; ++nt) {
            acc1[nt] = __builtin_amdgcn_mfma_f32_16x16x32_f16(ah, bh[nt], acc1[nt], 0, 0, 0);
            acc2[nt] = __builtin_amdgcn_mfma_f32_16x16x32_f16(ah, bl[nt], acc2[nt], 0, 0, 0);
            acc2[nt] = __builtin_amdgcn_mfma_f32_16x16x32_f16(al, bh[nt], acc2[nt], 0, 0, 0);
        }
        if (kt < 15) {
            ah = nah; al = nal;
#pragma unroll
            for (int nt = 0; nt < 4; ++nt) { bh[nt] = nbh[nt]; bl[nt] = nbl[nt]; }
        }
    }

    int nloc = lane & 15;
    int mrow = mt * 16 + (lane >> 4) * 4;
    if (ntb < 128) {                     // gates tiles -> write-through
        float* g = ws + OFF_G;
#pragma unroll
        for (int nt = 0; nt < 4; ++nt) {
            int n = (ntb + nt) * 16 + nloc;
#pragma unroll
            for (int r = 0; r < 4; ++r)
                st_wt(&g[(size_t)(mrow + r) * FD + n],
                      acc1[nt][r] + acc2[nt][r] * INV_LOSCALE);
        }
    } else {                             // logits tiles
        int tout = tau - 1;
#pragma unroll
        for (int nt = 0; nt < 4; ++nt) {
            int v = (ntb + nt) * 16 + nloc - FD;
#pragma unroll
            for (int r = 0; r < 4; ++r) {
                int b = mrow + r;
                float val = acc1[nt][r] + acc2[nt][r] * INV_LOSCALE;
                float lg = val - ws[OFF_CP + (size_t)b * VDIM + v] + proj_b[v];
                out[((size_t)b * VDIM + v) * TDIM + tout] = lg;
                st_wt(&ws[OFF_LC + (size_t)b * VDIM + v], lg);
            }
        }
    }
}

// ---------------------------------------------------------------------------
// One tick = one launch. Each block does its GEMM job; __syncthreads drains
// all waves' write-through stores (compiler emits s_waitcnt vmcnt(0) before
// s_barrier); last arrival per rt (relaxed device-scope counter) runs the
// pointwise phase for its 64-row band: argmax -> E-gather -> LSTM -> A-frags.
// A-frags / c are ordinary stores: consumed only by the NEXT launch
// (stream-order kernel-boundary coherence, as rounds 1-3).
// ---------------------------------------------------------------------------
__global__ __launch_bounds__(256) void k_tick(
        const float* __restrict__ proj_b, const int* __restrict__ sos_p,
        float* __restrict__ ws, float* __restrict__ out,
        int ctOff, int tau, int expected, int doP, int doArg)
{
    int rt = blockIdx.x;                 // 0..15
    int ct = blockIdx.y + ctOff;         // 0..33
    int tid = threadIdx.x;

    gemm_job(rt, ct, tid >> 6, tid & 63, proj_b, ws, out, tau);

    if (!doP) return;

    __shared__ int s_lastflag;
    __syncthreads();                     // drains every wave's vm stores
    if (tid == 0) {
        unsigned old = __hip_atomic_fetch_add(&g_cnt[tau * 16 + rt], 1u,
                                              __ATOMIC_RELAXED,
                                              __HIP_MEMORY_SCOPE_AGENT);
        s_lastflag = (old == (unsigned)(expected - 1));
    }
    __syncthreads();
    if (!s_lastflag) return;

    // ---------------- P phase: rows [rt*64, rt*64+64) ----------------
    __shared__ float s_lc[64][129];      // pad 129: argmax scan conflict-free
    __shared__ int   s_id[64];
    int row0 = rt * 64;

    if (doArg) {
        for (int i = tid; i < 64 * VDIM; i += 256) {
            int r = i >> 7, v = i & 127;
            s_lc[r][v] = ld_wt(ws + OFF_LC + (size_t)(row0 + r) * VDIM + v);
        }
        __syncthreads();
        if (tid < 64) {
            float best = s_lc[tid][0];
            int bi = 0;
            for (int v = 1; v < VDIM; ++v) {
                float x = s_lc[tid][v];
                if (x > best) { best = x; bi = v; }   // first-index ties (jnp)
            }
            s_id[tid] = bi;
        }
    } else {
        if (tid < 64) s_id[tid] = sos_p[0];
    }
    __syncthreads();

    _Float16* Ahi = (_Float16*)(ws + OFF_AHI);
    _Float16* Alo = (_Float16*)(ws + OFF_ALO);

    for (int i = tid; i < 64 * DDIM; i += 256) {
        int r = i >> 9, d = i & 511;
        int row = row0 + r;
        const float* g   = ws + OFF_G   + (size_t)row * FD;
        const float* E   = ws + OFF_E   + (size_t)s_id[r] * FD;
        const float* ctx = ws + OFF_CTX + (size_t)row * DDIM;
        float* cp = ws + OFF_C + (size_t)row * DDIM + d;

        float gi = ld_wt(g + d)            + E[d];
        float gf = ld_wt(g + d + DDIM)     + E[d + DDIM];
        float gg = ld_wt(g + d + 2 * DDIM) + E[d + 2 * DDIM];
        float go = ld_wt(g + d + 3 * DDIM) + E[d + 3 * DDIM];
        float cv = *cp;
        float si = 1.0f / (1.0f + expf(-gi));
        float sf = 1.0f / (1.0f + expf(-gf));
        float so = 1.0f / (1.0f + expf(-go));
        float cn = sf * cv + si * tanhf(gg);
        *cp = cn;
        float hn = so * tanhf(cn);
        split_write(hn + ctx[d], Ahi, Alo, row, d);
    }
}

extern "C" void kernel_launch(void* const* d_in, const int* in_sizes, int n_in,
                              void* d_out, int out_size, void* d_ws, size_t ws_size,
                              hipStream_t stream)
{
    const float* fm     = (const float*)d_in[0];
    const float* pooled = (const float*)d_in[1];
    const float* gamma  = (const float*)d_in[2];
    const float* beta   = (const float*)d_in[3];
    const float* W_ih   = (const float*)d_in[4];
    const float* W_hh   = (const float*)d_in[5];
    const float* b_ih   = (const float*)d_in[6];
    const float* b_hh   = (const float*)d_in[7];
    const float* embed  = (const float*)d_in[8];
    const float* attn_w = (const float*)d_in[9];
    // d_in[10] = attn_b : provably unused (softmax shift invariance)
    const float* proj_w = (const float*)d_in[11];
    const float* proj_b = (const float*)d_in[12];
    const int*   sos_p  = (const int*)d_in[13];

    float* ws  = (float*)d_ws;
    float* out = (float*)d_out;

    k_init<<<BDIM, 256, 0, stream>>>(fm, pooled, gamma, beta, attn_w, ws);
    k_E<<<FD, 256, 0, stream>>>(embed, W_ih, b_ih, b_hh, ws);
    k_cp<<<BDIM, 128, 0, stream>>>(proj_w, ws);
    k_bsetup<<<FD + VDIM, 256, 0, stream>>>(W_hh, proj_w, ws);
    k_zero<<<13, 256, 0, stream>>>();

    // tick 0: gates only (32 col tiles), P uses sos (no argmax)
    k_tick<<<dim3(16, 32), 256, 0, stream>>>(proj_b, sos_p, ws, out, 0, 0, 32, 1, 0);

    // ticks 1..200: full 34 col tiles; logits of tau-1 + gates of tau; P w/ argmax
    for (int tau = 1; tau <= 200; ++tau)
        k_tick<<<dim3(16, 34), 256, 0, stream>>>(proj_b, sos_p, ws, out, 0, tau, 34, 1, 1);

    // tick 201: logits of step 200 only; no P
    k_tick<<<dim3(16, 2), 256, 0, stream>>>(proj_b, sos_p, ws, out, 32, 201, 0, 0, 0);
}